// Round 3
// baseline (650.401 us; speedup 1.0000x reference)
//
#include <hip/hip_runtime.h>
#include <stdint.h>

typedef __bf16 bf16;
typedef __attribute__((ext_vector_type(8))) bf16 bf16x8;
typedef __attribute__((ext_vector_type(4))) float f32x4;

#define D 64
#define EPW 32   // edges per wave-tile

__device__ __forceinline__ float silu_f(float x) {
    return x / (1.0f + __expf(-x));
}

// ---------------------------------------------------------------------------
// Counting sort by edge_dst: histogram -> exclusive scan -> scatter.
// Gives eperm s.t. edst[eperm[i]] is non-decreasing (bucket-contiguous).
// ---------------------------------------------------------------------------
__global__ void hist_kernel(const int* __restrict__ edst, int* __restrict__ cnt, int E) {
    const int stride = gridDim.x * blockDim.x;
    for (int e = blockIdx.x * blockDim.x + threadIdx.x; e < E; e += stride)
        atomicAdd(&cnt[edst[e]], 1);
}

__global__ void scan_kernel(const int* __restrict__ cnt, int* __restrict__ cur, int n) {
    __shared__ int part[1024];
    const int t  = threadIdx.x;
    const int CH = (n + 1023) >> 10;
    const int base = t * CH;
    int s = 0;
    for (int i = 0; i < CH; ++i) { int idx = base + i; if (idx < n) s += cnt[idx]; }
    part[t] = s;
    __syncthreads();
    for (int off = 1; off < 1024; off <<= 1) {   // Hillis-Steele inclusive
        int v = (t >= off) ? part[t - off] : 0;
        __syncthreads();
        part[t] += v;
        __syncthreads();
    }
    int run = (t == 0) ? 0 : part[t - 1];
    for (int i = 0; i < CH; ++i) {
        int idx = base + i;
        if (idx < n) { cur[idx] = run; run += cnt[idx]; }
    }
}

__global__ void scatter_kernel(const int* __restrict__ edst, int* __restrict__ cur,
                               int* __restrict__ eperm, int E) {
    const int stride = gridDim.x * blockDim.x;
    for (int e = blockIdx.x * blockDim.x + threadIdx.x; e < E; e += stride) {
        int pos = atomicAdd(&cur[edst[e]], 1);
        eperm[pos] = e;
    }
}

// ---------------------------------------------------------------------------
// Edge message MLP (bf16 MFMA) over dst-sorted edges + run-reduced aggregation.
// Each wave owns a 32-edge tile. A-fragments loaded directly from global.
// After GEMM2, messages (+bias) go to per-wave LDS Ms[32][64] (bf16); runs of
// equal dst are summed per-column (lane=col) and written once: interior runs
// (a>0 && b<32, provably the dst's whole range when sorted) -> plain store;
// boundary runs -> atomicAdd. agg must be pre-zeroed.
// K-slot convention k' = 32*ks + 8*(lane>>4) + i for BOTH A and B fragments.
// C/D layout: col = nt*16 + (lane&15), row = 4*(lane>>4) + reg.
// ---------------------------------------------------------------------------
__launch_bounds__(256, 2)
__global__ void mp_edge_kernel(
    const float* __restrict__ node_feat,
    const int*   __restrict__ esrc,
    const int*   __restrict__ edst,
    const float* __restrict__ efeat,
    const int*   __restrict__ eperm,   // may be null (identity)
    const int    sorted,               // 1: interior runs may plain-store
    const float* __restrict__ W1, const float* __restrict__ b1,
    const float* __restrict__ W2, const float* __restrict__ b2,
    float* __restrict__ agg,
    int E)
{
    __shared__ __align__(16) bf16 W1f[6*4*64*8];   // 24 KB (ks,nt,lane,8)
    __shared__ __align__(16) bf16 W2f[2*4*64*8];   //  8 KB
    __shared__ __align__(16) bf16 Hs[4][32*72];    // 18 KB per-wave hidden
    __shared__ __align__(16) bf16 Ms[4][32*64];    // 16 KB per-wave messages
    __shared__ float b1s[D], b2s[D];

    const int t    = threadIdx.x;
    const int lane = t & 63;
    const int w    = t >> 6;
    const int g    = lane >> 4;
    const int c    = lane & 15;

    // ---- stage W1/W2 as MFMA B-fragments (once per block) ----
    for (int idx = t; idx < 6*4*64; idx += 256) {
        int l = idx & 63, nt = (idx >> 6) & 3, ks = idx >> 8;
        int k0 = ks*32 + (l >> 4)*8, col = nt*16 + (l & 15);
        bf16x8 v;
        #pragma unroll
        for (int i = 0; i < 8; ++i) v[i] = (bf16)W1[(k0 + i)*D + col];
        *(bf16x8*)&W1f[idx*8] = v;
    }
    for (int idx = t; idx < 2*4*64; idx += 256) {
        int l = idx & 63, nt = (idx >> 6) & 3, ks = idx >> 8;
        int k0 = ks*32 + (l >> 4)*8, col = nt*16 + (l & 15);
        bf16x8 v;
        #pragma unroll
        for (int i = 0; i < 8; ++i) v[i] = (bf16)W2[(k0 + i)*D + col];
        *(bf16x8*)&W2f[idx*8] = v;
    }
    if (t < D) { b1s[t] = b1[t]; b2s[t] = b2[t]; }
    __syncthreads();   // weights ready; the ONLY barrier

    bf16* hs = &Hs[w][0];
    bf16* ms = &Ms[w][0];
    const int nwt = (E + EPW - 1) / EPW;

    for (int tile = blockIdx.x*4 + w; tile < nwt; tile += gridDim.x*4) {
        const int e0 = tile * EPW;
        const int r0 = min(e0 + c,      E - 1);
        const int r1 = min(e0 + 16 + c, E - 1);
        const int ea = eperm ? eperm[r0] : r0;
        const int eb = eperm ? eperm[r1] : r1;
        const int se0 = esrc[ea], de0 = edst[ea];
        const int se1 = esrc[eb], de1 = edst[eb];

        // ---- GEMM1: [32,192]@[192,64], A direct from global ----
        f32x4 acc0[4] = {f32x4{0,0,0,0}, f32x4{0,0,0,0}, f32x4{0,0,0,0}, f32x4{0,0,0,0}};
        f32x4 acc1[4] = {f32x4{0,0,0,0}, f32x4{0,0,0,0}, f32x4{0,0,0,0}, f32x4{0,0,0,0}};
        #pragma unroll
        for (int ks = 0; ks < 6; ++ks) {
            const int col = ks*32 + g*8;
            const float *p0, *p1;
            if (col < 64) {
                p0 = node_feat + (size_t)se0*D + col;
                p1 = node_feat + (size_t)se1*D + col;
            } else if (col < 128) {
                p0 = node_feat + (size_t)de0*D + (col - 64);
                p1 = node_feat + (size_t)de1*D + (col - 64);
            } else {
                p0 = efeat + (size_t)ea*D + (col - 128);
                p1 = efeat + (size_t)eb*D + (col - 128);
            }
            f32x4 xa = ((const f32x4*)p0)[0], xb = ((const f32x4*)p0)[1];
            f32x4 ya = ((const f32x4*)p1)[0], yb = ((const f32x4*)p1)[1];
            bf16x8 a0, a1;
            #pragma unroll
            for (int i = 0; i < 4; ++i) {
                a0[i] = (bf16)xa[i];  a0[4+i] = (bf16)xb[i];
                a1[i] = (bf16)ya[i];  a1[4+i] = (bf16)yb[i];
            }
            #pragma unroll
            for (int n = 0; n < 4; ++n) {
                bf16x8 bb = *(const bf16x8*)&W1f[((ks*4 + n)*64 + lane)*8];
                acc0[n] = __builtin_amdgcn_mfma_f32_16x16x32_bf16(a0, bb, acc0[n], 0, 0, 0);
                acc1[n] = __builtin_amdgcn_mfma_f32_16x16x32_bf16(a1, bb, acc1[n], 0, 0, 0);
            }
        }

        // ---- bias + SiLU -> per-wave Hs (bf16) ----
        #pragma unroll
        for (int n = 0; n < 4; ++n) {
            const int col = n*16 + c;
            const float bias = b1s[col];
            #pragma unroll
            for (int j = 0; j < 4; ++j) {
                hs[(g*4 + j)*72 + col]      = (bf16)silu_f(acc0[n][j] + bias);
                hs[(16 + g*4 + j)*72 + col] = (bf16)silu_f(acc1[n][j] + bias);
            }
        }

        // ---- GEMM2: [32,64]@[64,64] (intra-wave LDS ordering) ----
        f32x4 acc2a[4] = {f32x4{0,0,0,0}, f32x4{0,0,0,0}, f32x4{0,0,0,0}, f32x4{0,0,0,0}};
        f32x4 acc2b[4] = {f32x4{0,0,0,0}, f32x4{0,0,0,0}, f32x4{0,0,0,0}, f32x4{0,0,0,0}};
        #pragma unroll
        for (int ks = 0; ks < 2; ++ks) {
            bf16x8 a0 = *(const bf16x8*)&hs[c*72        + ks*32 + g*8];
            bf16x8 a1 = *(const bf16x8*)&hs[(16 + c)*72 + ks*32 + g*8];
            #pragma unroll
            for (int n = 0; n < 4; ++n) {
                bf16x8 bb = *(const bf16x8*)&W2f[((ks*4 + n)*64 + lane)*8];
                acc2a[n] = __builtin_amdgcn_mfma_f32_16x16x32_bf16(a0, bb, acc2a[n], 0, 0, 0);
                acc2b[n] = __builtin_amdgcn_mfma_f32_16x16x32_bf16(a1, bb, acc2b[n], 0, 0, 0);
            }
        }

        // ---- messages (+bias) -> per-wave Ms (bf16) ----
        #pragma unroll
        for (int n = 0; n < 4; ++n) {
            const int col = n*16 + c;
            const float bias = b2s[col];
            #pragma unroll
            for (int j = 0; j < 4; ++j) {
                ms[(g*4 + j)*64 + col]      = (bf16)(acc2a[n][j] + bias);
                ms[(16 + g*4 + j)*64 + col] = (bf16)(acc2b[n][j] + bias);
            }
        }

        // ---- run detection over the 32 sorted rows ----
        // lane r (0..31) obtains dst of row r via shfl from the loader lanes
        const int da = __shfl(de0, lane & 15);
        const int db = __shfl(de1, lane & 15);
        const int row = lane & 31;
        int rowd = (lane & 16) ? db : da;
        if (e0 + row >= E) rowd = -1;                 // invalid tail rows
        const int prevd = __shfl(rowd, (lane + 63) & 63);
        const bool st = (row == 0) || (rowd != prevd);
        unsigned long long m = __ballot(st) & 0xFFFFFFFFull;   // lanes 0..31

        // ---- per-run column sums (lane = col), one write per run ----
        while (m) {
            const int a = __builtin_ctzll(m); m &= m - 1;
            const int b = m ? __builtin_ctzll(m) : 32;
            const int d = __shfl(rowd, a);
            if (d >= 0) {
                float s = 0.f;
                for (int r = a; r < b; ++r) s += (float)ms[r*64 + lane];
                float* dp = &agg[(size_t)d*D + lane];
                if (sorted && a > 0 && b < 32) *dp = s;   // whole range in-tile
                else atomicAdd(dp, s);                    // boundary run
            }
        }
    }
}

// ---------------------------------------------------------------------------
// Node update MLP (fp32) + residual + LayerNorm, in-place on agg.
// One wave per node; lane j owns output dim j; k-broadcast via __shfl.
// ---------------------------------------------------------------------------
__launch_bounds__(256, 4)
__global__ void mp_node_kernel(
    const float* __restrict__ node_feat,
    const float* __restrict__ Wu1, const float* __restrict__ bu1,
    const float* __restrict__ Wu2, const float* __restrict__ bu2,
    const float* __restrict__ gamma, const float* __restrict__ beta,
    float* __restrict__ inout,
    int nnodes)
{
    __shared__ __align__(16) float W1t[64*68];
    __shared__ __align__(16) float W2t[64*68];
    __shared__ float b1s[D], b2s[D], gs[D], bs[D];

    const int t = threadIdx.x, lane = t & 63, w = t >> 6;
    for (int idx = t; idx < 4096; idx += 256) {
        int j = idx & 63, k = idx >> 6;
        W1t[j*68 + k] = Wu1[k*D + j];
        W2t[j*68 + k] = Wu2[k*D + j];
    }
    if (t < D) { b1s[t] = bu1[t]; b2s[t] = bu2[t]; gs[t] = gamma[t]; bs[t] = beta[t]; }
    __syncthreads();

    for (int n = blockIdx.x*4 + w; n < nnodes; n += gridDim.x*4) {
        float a  = inout[(size_t)n*D + lane];
        float x0 = node_feat[(size_t)n*D + lane];

        float acc = b1s[lane];
        #pragma unroll
        for (int k4 = 0; k4 < 16; ++k4) {
            f32x4 wv = *(const f32x4*)&W1t[lane*68 + k4*4];
            acc += __shfl(a, k4*4+0)*wv[0] + __shfl(a, k4*4+1)*wv[1]
                 + __shfl(a, k4*4+2)*wv[2] + __shfl(a, k4*4+3)*wv[3];
        }
        float h = silu_f(acc);

        float acc2 = b2s[lane];
        #pragma unroll
        for (int k4 = 0; k4 < 16; ++k4) {
            f32x4 wv = *(const f32x4*)&W2t[lane*68 + k4*4];
            acc2 += __shfl(h, k4*4+0)*wv[0] + __shfl(h, k4*4+1)*wv[1]
                  + __shfl(h, k4*4+2)*wv[2] + __shfl(h, k4*4+3)*wv[3];
        }

        float y = x0 + acc2;
        float s1 = y, s2 = y*y;
        #pragma unroll
        for (int off = 32; off > 0; off >>= 1) {
            s1 += __shfl_xor(s1, off);
            s2 += __shfl_xor(s2, off);
        }
        float mu  = s1 * (1.0f/64.0f);
        float var = s2 * (1.0f/64.0f) - mu*mu;
        float rs  = rsqrtf(var + 1e-5f);
        inout[(size_t)n*D + lane] = (y - mu)*rs*gs[lane] + bs[lane];
    }
}

extern "C" void kernel_launch(void* const* d_in, const int* in_sizes, int n_in,
                              void* d_out, int out_size, void* d_ws, size_t ws_size,
                              hipStream_t stream) {
    const float* node_feat = (const float*)d_in[0];
    const int*   esrc      = (const int*)d_in[1];
    const int*   edst      = (const int*)d_in[2];
    const float* efeat     = (const float*)d_in[3];
    const float* W_m1      = (const float*)d_in[4];
    const float* b_m1      = (const float*)d_in[5];
    const float* W_m2      = (const float*)d_in[6];
    const float* b_m2      = (const float*)d_in[7];
    const float* W_u1      = (const float*)d_in[8];
    const float* b_u1      = (const float*)d_in[9];
    const float* W_u2      = (const float*)d_in[10];
    const float* b_u2      = (const float*)d_in[11];
    const float* ln_gamma  = (const float*)d_in[12];
    const float* ln_beta   = (const float*)d_in[13];

    float* out = (float*)d_out;
    const int E      = in_sizes[1];
    const int nnodes = in_sizes[0] / D;

    hipMemsetAsync(out, 0, (size_t)nnodes * D * sizeof(float), stream);

    // workspace layout: eperm[E] | cnt[nnodes] | cur[nnodes]
    const size_t need = sizeof(int) * ((size_t)E + 2*(size_t)nnodes);
    int* eperm = nullptr;
    int  sorted = 0;
    if (ws_size >= need) {
        eperm    = (int*)d_ws;
        int* cnt = eperm + E;
        int* cur = cnt + nnodes;
        sorted = 1;
        hipMemsetAsync(cnt, 0, sizeof(int)*(size_t)nnodes, stream);
        hist_kernel   <<<1024, 256, 0, stream>>>(edst, cnt, E);
        scan_kernel   <<<1, 1024, 0, stream>>>(cnt, cur, nnodes);
        scatter_kernel<<<1024, 256, 0, stream>>>(edst, cur, eperm, E);
    }

    const int nwt   = (E + EPW - 1) / EPW;
    const int nblk  = (nwt + 3) / 4;
    const int grid1 = nblk < 2048 ? nblk : 2048;
    mp_edge_kernel<<<grid1, 256, 0, stream>>>(node_feat, esrc, edst, efeat,
                                              eperm, sorted,
                                              W_m1, b_m1, W_m2, b_m2,
                                              out, E);

    mp_node_kernel<<<2048, 256, 0, stream>>>(node_feat, W_u1, b_u1, W_u2, b_u2,
                                             ln_gamma, ln_beta, out, nnodes);
}

// Round 4
// 378.618 us; speedup vs baseline: 1.7178x; 1.7178x over previous
//
#include <hip/hip_runtime.h>
#include <stdint.h>

typedef __bf16 bf16;
typedef __attribute__((ext_vector_type(8))) bf16 bf16x8;
typedef __attribute__((ext_vector_type(4))) float f32x4;

#define D 64
#define EPW 32   // edges per wave-tile

__device__ __forceinline__ float silu_f(float x) {
    return x / (1.0f + __expf(-x));
}

// ---------------------------------------------------------------------------
// Counting sort by edge_dst (CSR build): hist -> 3-kernel scan -> scatter.
// ---------------------------------------------------------------------------
__global__ void hist_kernel(const int* __restrict__ edst, int* __restrict__ cnt, int E) {
    const int stride = gridDim.x * blockDim.x;
    for (int e = blockIdx.x * blockDim.x + threadIdx.x; e < E; e += stride)
        atomicAdd(&cnt[edst[e]], 1);
}

__global__ void scan_part_kernel(const int* __restrict__ cnt, int* __restrict__ part, int N) {
    __shared__ int red[256];
    const int t = threadIdx.x, idx = blockIdx.x * 256 + t;
    red[t] = (idx < N) ? cnt[idx] : 0;
    __syncthreads();
    for (int off = 128; off; off >>= 1) {
        if (t < off) red[t] += red[t + off];
        __syncthreads();
    }
    if (t == 0) part[blockIdx.x] = red[0];
}

__global__ void scan_base_kernel(int* __restrict__ part, int nblk) {
    __shared__ int sc[256];
    const int t = threadIdx.x;
    const int v = (t < nblk) ? part[t] : 0;
    sc[t] = v;
    __syncthreads();
    for (int off = 1; off < 256; off <<= 1) {
        int u = (t >= off) ? sc[t - off] : 0;
        __syncthreads();
        sc[t] += u;
        __syncthreads();
    }
    part[t] = sc[t] - v;   // exclusive base per block
}

__global__ void scan_fin_kernel(const int* __restrict__ cnt, const int* __restrict__ part,
                                int* __restrict__ cur, int* __restrict__ rstart, int N) {
    __shared__ int sc[256];
    const int t = threadIdx.x, idx = blockIdx.x * 256 + t;
    const int v = (idx < N) ? cnt[idx] : 0;
    sc[t] = v;
    __syncthreads();
    for (int off = 1; off < 256; off <<= 1) {
        int u = (t >= off) ? sc[t - off] : 0;
        __syncthreads();
        sc[t] += u;
        __syncthreads();
    }
    const int excl = sc[t] - v + part[blockIdx.x];
    if (idx < N) { cur[idx] = excl; rstart[idx] = excl; }
}

__global__ void scatter_kernel(const int* __restrict__ edst, int* __restrict__ cur,
                               int* __restrict__ eperm, int E) {
    const int stride = gridDim.x * blockDim.x;
    for (int e = blockIdx.x * blockDim.x + threadIdx.x; e < E; e += stride) {
        int pos = atomicAdd(&cur[edst[e]], 1);
        eperm[pos] = e;
    }
}

// ---------------------------------------------------------------------------
// Edge message MLP (bf16 MFMA), ORIGINAL edge order (efeat streams).
// msgbuf != null: dense bf16 message store (no atomics).
// msgbuf == null: fallback atomic scatter-add into agg (must be pre-zeroed).
// K-slot convention k' = 32*ks + 8*(lane>>4) + i for BOTH A and B fragments.
// C/D layout: col = nt*16 + (lane&15), row = 4*(lane>>4) + reg.
// ---------------------------------------------------------------------------
__launch_bounds__(256, 2)
__global__ void mp_edge_kernel(
    const float* __restrict__ node_feat,
    const int*   __restrict__ esrc,
    const int*   __restrict__ edst,
    const float* __restrict__ efeat,
    const float* __restrict__ W1, const float* __restrict__ b1,
    const float* __restrict__ W2, const float* __restrict__ b2,
    bf16* __restrict__ msgbuf,     // dense [E][64] messages, or null
    float* __restrict__ agg,       // fallback atomic target, or null
    int E)
{
    __shared__ __align__(16) bf16 W1f[6*4*64*8];   // 24 KB (ks,nt,lane,8)
    __shared__ __align__(16) bf16 W2f[2*4*64*8];   //  8 KB
    __shared__ __align__(16) bf16 Hs[4][32*72];    // 18 KB per-wave hidden
    __shared__ __align__(16) bf16 Ms[4][32*64];    // 16 KB per-wave messages
    __shared__ float b1s[D], b2s[D];

    const int t    = threadIdx.x;
    const int lane = t & 63;
    const int w    = t >> 6;
    const int g    = lane >> 4;
    const int c    = lane & 15;

    for (int idx = t; idx < 6*4*64; idx += 256) {
        int l = idx & 63, nt = (idx >> 6) & 3, ks = idx >> 8;
        int k0 = ks*32 + (l >> 4)*8, col = nt*16 + (l & 15);
        bf16x8 v;
        #pragma unroll
        for (int i = 0; i < 8; ++i) v[i] = (bf16)W1[(k0 + i)*D + col];
        *(bf16x8*)&W1f[idx*8] = v;
    }
    for (int idx = t; idx < 2*4*64; idx += 256) {
        int l = idx & 63, nt = (idx >> 6) & 3, ks = idx >> 8;
        int k0 = ks*32 + (l >> 4)*8, col = nt*16 + (l & 15);
        bf16x8 v;
        #pragma unroll
        for (int i = 0; i < 8; ++i) v[i] = (bf16)W2[(k0 + i)*D + col];
        *(bf16x8*)&W2f[idx*8] = v;
    }
    if (t < D) { b1s[t] = b1[t]; b2s[t] = b2[t]; }
    __syncthreads();   // weights ready; the ONLY barrier

    bf16* hs = &Hs[w][0];
    bf16* ms = &Ms[w][0];
    const int nwt = (E + EPW - 1) / EPW;

    for (int tile = blockIdx.x*4 + w; tile < nwt; tile += gridDim.x*4) {
        const int e0 = tile * EPW;
        const int r0 = min(e0 + c,      E - 1);
        const int r1 = min(e0 + 16 + c, E - 1);
        const int se0 = esrc[r0], de0 = edst[r0];
        const int se1 = esrc[r1], de1 = edst[r1];

        // ---- GEMM1: [32,192]@[192,64], A direct from global ----
        f32x4 acc0[4] = {f32x4{0,0,0,0}, f32x4{0,0,0,0}, f32x4{0,0,0,0}, f32x4{0,0,0,0}};
        f32x4 acc1[4] = {f32x4{0,0,0,0}, f32x4{0,0,0,0}, f32x4{0,0,0,0}, f32x4{0,0,0,0}};
        #pragma unroll
        for (int ks = 0; ks < 6; ++ks) {
            const int col = ks*32 + g*8;
            const float *p0, *p1;
            if (col < 64) {
                p0 = node_feat + (size_t)se0*D + col;
                p1 = node_feat + (size_t)se1*D + col;
            } else if (col < 128) {
                p0 = node_feat + (size_t)de0*D + (col - 64);
                p1 = node_feat + (size_t)de1*D + (col - 64);
            } else {
                p0 = efeat + (size_t)r0*D + (col - 128);
                p1 = efeat + (size_t)r1*D + (col - 128);
            }
            f32x4 xa = ((const f32x4*)p0)[0], xb = ((const f32x4*)p0)[1];
            f32x4 ya = ((const f32x4*)p1)[0], yb = ((const f32x4*)p1)[1];
            bf16x8 a0, a1;
            #pragma unroll
            for (int i = 0; i < 4; ++i) {
                a0[i] = (bf16)xa[i];  a0[4+i] = (bf16)xb[i];
                a1[i] = (bf16)ya[i];  a1[4+i] = (bf16)yb[i];
            }
            #pragma unroll
            for (int n = 0; n < 4; ++n) {
                bf16x8 bb = *(const bf16x8*)&W1f[((ks*4 + n)*64 + lane)*8];
                acc0[n] = __builtin_amdgcn_mfma_f32_16x16x32_bf16(a0, bb, acc0[n], 0, 0, 0);
                acc1[n] = __builtin_amdgcn_mfma_f32_16x16x32_bf16(a1, bb, acc1[n], 0, 0, 0);
            }
        }

        // ---- bias + SiLU -> per-wave Hs (bf16) ----
        #pragma unroll
        for (int n = 0; n < 4; ++n) {
            const int col = n*16 + c;
            const float bias = b1s[col];
            #pragma unroll
            for (int j = 0; j < 4; ++j) {
                hs[(g*4 + j)*72 + col]      = (bf16)silu_f(acc0[n][j] + bias);
                hs[(16 + g*4 + j)*72 + col] = (bf16)silu_f(acc1[n][j] + bias);
            }
        }

        // ---- GEMM2: [32,64]@[64,64] (intra-wave LDS ordering) ----
        f32x4 acc2a[4] = {f32x4{0,0,0,0}, f32x4{0,0,0,0}, f32x4{0,0,0,0}, f32x4{0,0,0,0}};
        f32x4 acc2b[4] = {f32x4{0,0,0,0}, f32x4{0,0,0,0}, f32x4{0,0,0,0}, f32x4{0,0,0,0}};
        #pragma unroll
        for (int ks = 0; ks < 2; ++ks) {
            bf16x8 a0 = *(const bf16x8*)&hs[c*72        + ks*32 + g*8];
            bf16x8 a1 = *(const bf16x8*)&hs[(16 + c)*72 + ks*32 + g*8];
            #pragma unroll
            for (int n = 0; n < 4; ++n) {
                bf16x8 bb = *(const bf16x8*)&W2f[((ks*4 + n)*64 + lane)*8];
                acc2a[n] = __builtin_amdgcn_mfma_f32_16x16x32_bf16(a0, bb, acc2a[n], 0, 0, 0);
                acc2b[n] = __builtin_amdgcn_mfma_f32_16x16x32_bf16(a1, bb, acc2b[n], 0, 0, 0);
            }
        }

        if (msgbuf) {
            // ---- messages (+bias) -> Ms -> dense contiguous bf16 store ----
            #pragma unroll
            for (int n = 0; n < 4; ++n) {
                const int col = n*16 + c;
                const float bias = b2s[col];
                #pragma unroll
                for (int j = 0; j < 4; ++j) {
                    ms[(g*4 + j)*64 + col]      = (bf16)(acc2a[n][j] + bias);
                    ms[(16 + g*4 + j)*64 + col] = (bf16)(acc2b[n][j] + bias);
                }
            }
            // 32 rows x 128B = 4 KB contiguous, 4 passes of 64 lanes x 16B
            #pragma unroll
            for (int i = lane; i < 256; i += 64) {
                if (e0 + (i >> 3) < E)
                    *(bf16x8*)&msgbuf[(size_t)e0*64 + i*8] = *(const bf16x8*)&ms[i*8];
            }
        } else {
            // ---- fallback: atomic scatter-add ----
            #pragma unroll
            for (int j = 0; j < 4; ++j) {
                const int row = g*4 + j;
                const int d0 = __shfl(de0, row);
                const int d1 = __shfl(de1, row);
                const bool ok0 = (e0 + row)      < E;
                const bool ok1 = (e0 + 16 + row) < E;
                #pragma unroll
                for (int n = 0; n < 4; ++n) {
                    const int col = n*16 + c;
                    if (ok0) atomicAdd(&agg[(size_t)d0*D + col], acc2a[n][j] + b2s[col]);
                    if (ok1) atomicAdd(&agg[(size_t)d1*D + col], acc2b[n][j] + b2s[col]);
                }
            }
        }
    }
}

// ---------------------------------------------------------------------------
// CSR aggregate: one wave per node; lane = column; sum msgbuf rows of the run.
// Writes every node's row (no memset needed).
// ---------------------------------------------------------------------------
__launch_bounds__(256, 8)
__global__ void agg_kernel(const bf16* __restrict__ msgbuf,
                           const int* __restrict__ eperm,
                           const int* __restrict__ rstart,
                           float* __restrict__ agg,
                           int N, int E)
{
    const int lane = threadIdx.x & 63;
    const int w    = threadIdx.x >> 6;
    for (int n = blockIdx.x*4 + w; n < N; n += gridDim.x*4) {
        const int beg = rstart[n];
        const int end = (n + 1 < N) ? rstart[n + 1] : E;
        float s0 = 0.f, s1 = 0.f, s2 = 0.f, s3 = 0.f;
        int i = beg;
        for (; i + 4 <= end; i += 4) {
            int ea = eperm[i], eb = eperm[i+1], ec = eperm[i+2], ed = eperm[i+3];
            s0 += (float)msgbuf[(size_t)ea*64 + lane];
            s1 += (float)msgbuf[(size_t)eb*64 + lane];
            s2 += (float)msgbuf[(size_t)ec*64 + lane];
            s3 += (float)msgbuf[(size_t)ed*64 + lane];
        }
        for (; i < end; ++i) s0 += (float)msgbuf[(size_t)eperm[i]*64 + lane];
        agg[(size_t)n*D + lane] = (s0 + s1) + (s2 + s3);
    }
}

// ---------------------------------------------------------------------------
// Node update MLP as MFMA GEMM + residual + LayerNorm, in-place on agg.
// 64 rows/block (4 waves x 16). Same k-slot/C-layout conventions as edge.
// In-place safe: each wave reads only its own 16 rows (completed before its
// stores, lockstep program order); waves/blocks own disjoint rows.
// ---------------------------------------------------------------------------
__launch_bounds__(256, 4)
__global__ void node_gemm_kernel(
    const float* __restrict__ node_feat,
    const float* __restrict__ Wu1, const float* __restrict__ bu1,
    const float* __restrict__ Wu2, const float* __restrict__ bu2,
    const float* __restrict__ gamma, const float* __restrict__ beta,
    float* __restrict__ inout, int N)
{
    __shared__ __align__(16) bf16 Wf1[2*4*64*8];   // 8 KB
    __shared__ __align__(16) bf16 Wf2[2*4*64*8];   // 8 KB
    __shared__ __align__(16) bf16 Hs[4][16*72];    // 9 KB
    __shared__ float b1s[D], b2s[D], gs[D], bs[D];

    const int t    = threadIdx.x;
    const int lane = t & 63;
    const int w    = t >> 6;
    const int g    = lane >> 4;
    const int c    = lane & 15;

    for (int idx = t; idx < 2*4*64; idx += 256) {
        int l = idx & 63, nt = (idx >> 6) & 3, ks = idx >> 8;
        int k0 = ks*32 + (l >> 4)*8, col = nt*16 + (l & 15);
        bf16x8 v1, v2;
        #pragma unroll
        for (int i = 0; i < 8; ++i) {
            v1[i] = (bf16)Wu1[(k0 + i)*D + col];
            v2[i] = (bf16)Wu2[(k0 + i)*D + col];
        }
        *(bf16x8*)&Wf1[idx*8] = v1;
        *(bf16x8*)&Wf2[idx*8] = v2;
    }
    if (t < D) { b1s[t] = bu1[t]; b2s[t] = bu2[t]; gs[t] = gamma[t]; bs[t] = beta[t]; }
    __syncthreads();

    const int base = blockIdx.x*64 + w*16;
    if (base >= N) return;
    bf16* hs = &Hs[w][0];

    // ---- GEMM1: silu(agg @ Wu1 + b1) ----
    f32x4 acc[4] = {f32x4{0,0,0,0}, f32x4{0,0,0,0}, f32x4{0,0,0,0}, f32x4{0,0,0,0}};
    #pragma unroll
    for (int ks = 0; ks < 2; ++ks) {
        const int rowA = min(base + c, N - 1);
        const float* p = inout + (size_t)rowA*D + ks*32 + g*8;
        f32x4 xa = ((const f32x4*)p)[0], xb = ((const f32x4*)p)[1];
        bf16x8 a;
        #pragma unroll
        for (int i = 0; i < 4; ++i) { a[i] = (bf16)xa[i]; a[4+i] = (bf16)xb[i]; }
        #pragma unroll
        for (int n = 0; n < 4; ++n) {
            bf16x8 bb = *(const bf16x8*)&Wf1[((ks*4 + n)*64 + lane)*8];
            acc[n] = __builtin_amdgcn_mfma_f32_16x16x32_bf16(a, bb, acc[n], 0, 0, 0);
        }
    }
    #pragma unroll
    for (int n = 0; n < 4; ++n) {
        const int col = n*16 + c;
        const float bias = b1s[col];
        #pragma unroll
        for (int j = 0; j < 4; ++j)
            hs[(g*4 + j)*72 + col] = (bf16)silu_f(acc[n][j] + bias);
    }

    // ---- GEMM2: h @ Wu2 ----
    f32x4 acc2[4] = {f32x4{0,0,0,0}, f32x4{0,0,0,0}, f32x4{0,0,0,0}, f32x4{0,0,0,0}};
    #pragma unroll
    for (int ks = 0; ks < 2; ++ks) {
        bf16x8 a = *(const bf16x8*)&hs[c*72 + ks*32 + g*8];
        #pragma unroll
        for (int n = 0; n < 4; ++n) {
            bf16x8 bb = *(const bf16x8*)&Wf2[((ks*4 + n)*64 + lane)*8];
            acc2[n] = __builtin_amdgcn_mfma_f32_16x16x32_bf16(a, bb, acc2[n], 0, 0, 0);
        }
    }

    // ---- residual + LayerNorm + store ----
    float y[4][4];
    #pragma unroll
    for (int n = 0; n < 4; ++n) {
        const int col = n*16 + c;
        #pragma unroll
        for (int j = 0; j < 4; ++j) {
            const int row = base + g*4 + j;
            const float x0 = (row < N) ? node_feat[(size_t)row*D + col] : 0.f;
            y[n][j] = x0 + acc2[n][j] + b2s[col];
        }
    }
    #pragma unroll
    for (int j = 0; j < 4; ++j) {
        float s1 = 0.f, s2 = 0.f;
        #pragma unroll
        for (int n = 0; n < 4; ++n) { s1 += y[n][j]; s2 += y[n][j]*y[n][j]; }
        #pragma unroll
        for (int m = 1; m < 16; m <<= 1) {
            s1 += __shfl_xor(s1, m);
            s2 += __shfl_xor(s2, m);
        }
        const float mu  = s1 * (1.0f/64.0f);
        const float var = s2 * (1.0f/64.0f) - mu*mu;
        const float rs  = rsqrtf(var + 1e-5f);
        const int row = base + g*4 + j;
        if (row < N) {
            #pragma unroll
            for (int n = 0; n < 4; ++n) {
                const int col = n*16 + c;
                inout[(size_t)row*D + col] = (y[n][j] - mu)*rs*gs[col] + bs[col];
            }
        }
    }
}

extern "C" void kernel_launch(void* const* d_in, const int* in_sizes, int n_in,
                              void* d_out, int out_size, void* d_ws, size_t ws_size,
                              hipStream_t stream) {
    const float* node_feat = (const float*)d_in[0];
    const int*   esrc      = (const int*)d_in[1];
    const int*   edst      = (const int*)d_in[2];
    const float* efeat     = (const float*)d_in[3];
    const float* W_m1      = (const float*)d_in[4];
    const float* b_m1      = (const float*)d_in[5];
    const float* W_m2      = (const float*)d_in[6];
    const float* b_m2      = (const float*)d_in[7];
    const float* W_u1      = (const float*)d_in[8];
    const float* b_u1      = (const float*)d_in[9];
    const float* W_u2      = (const float*)d_in[10];
    const float* b_u2      = (const float*)d_in[11];
    const float* ln_gamma  = (const float*)d_in[12];
    const float* ln_beta   = (const float*)d_in[13];

    float* out = (float*)d_out;
    const int E = in_sizes[1];
    const int N = in_sizes[0] / D;

    // workspace: msgbuf bf16[E*64] | eperm[E] | cnt[N] | cur[N] | rstart[N] | part[256]
    const size_t msg_bytes = (((size_t)E * 64 * 2) + 255) & ~(size_t)255;
    const size_t need = msg_bytes + sizeof(int) * ((size_t)E + 3*(size_t)N + 256);

    const int nwt   = (E + EPW - 1) / EPW;
    const int nblk  = (nwt + 3) / 4;
    const int grid1 = nblk < 2048 ? nblk : 2048;
    const int gridN = (N + 63) / 64;

    if (ws_size >= need) {
        bf16* msgbuf = (bf16*)d_ws;
        int* eperm   = (int*)((char*)d_ws + msg_bytes);
        int* cnt     = eperm + E;
        int* cur     = cnt + N;
        int* rstart  = cur + N;
        int* part    = rstart + N;
        const int nchunk = (N + 255) / 256;

        hipMemsetAsync(cnt, 0, sizeof(int)*(size_t)N, stream);
        hist_kernel     <<<1024, 256, 0, stream>>>(edst, cnt, E);
        scan_part_kernel<<<nchunk, 256, 0, stream>>>(cnt, part, N);
        scan_base_kernel<<<1, 256, 0, stream>>>(part, nchunk);
        scan_fin_kernel <<<nchunk, 256, 0, stream>>>(cnt, part, cur, rstart, N);
        scatter_kernel  <<<1024, 256, 0, stream>>>(edst, cur, eperm, E);

        mp_edge_kernel<<<grid1, 256, 0, stream>>>(node_feat, esrc, edst, efeat,
                                                  W_m1, b_m1, W_m2, b_m2,
                                                  msgbuf, nullptr, E);
        agg_kernel<<<2048, 256, 0, stream>>>(msgbuf, eperm, rstart, out, N, E);
    } else {
        hipMemsetAsync(out, 0, (size_t)N * D * sizeof(float), stream);
        mp_edge_kernel<<<grid1, 256, 0, stream>>>(node_feat, esrc, edst, efeat,
                                                  W_m1, b_m1, W_m2, b_m2,
                                                  nullptr, out, E);
    }

    node_gemm_kernel<<<gridN, 256, 0, stream>>>(node_feat, W_u1, b_u1, W_u2, b_u2,
                                                ln_gamma, ln_beta, out, N);
}

// Round 5
// 251.332 us; speedup vs baseline: 2.5878x; 1.5064x over previous
//
#include <hip/hip_runtime.h>
#include <stdint.h>

typedef __bf16 bf16;
typedef __attribute__((ext_vector_type(8))) bf16 bf16x8;
typedef __attribute__((ext_vector_type(4))) float f32x4;

#define D 64
#define EPW 32   // edges per wave-tile

__device__ __forceinline__ float silu_f(float x) {
    return x / (1.0f + __expf(-x));
}

// ---------------------------------------------------------------------------
// Counting sort by edge_dst: hist -> 3-kernel scan -> scatter (inverse perm).
// spos[e] = position of edge e in dst-sorted order (coalesced write).
// ---------------------------------------------------------------------------
__global__ void hist_kernel(const int* __restrict__ edst, int* __restrict__ cnt, int E) {
    const int stride = gridDim.x * blockDim.x;
    for (int e = blockIdx.x * blockDim.x + threadIdx.x; e < E; e += stride)
        atomicAdd(&cnt[edst[e]], 1);
}

__global__ void scan_part_kernel(const int* __restrict__ cnt, int* __restrict__ part, int N) {
    __shared__ int red[256];
    const int t = threadIdx.x, idx = blockIdx.x * 256 + t;
    red[t] = (idx < N) ? cnt[idx] : 0;
    __syncthreads();
    for (int off = 128; off; off >>= 1) {
        if (t < off) red[t] += red[t + off];
        __syncthreads();
    }
    if (t == 0) part[blockIdx.x] = red[0];
}

__global__ void scan_base_kernel(int* __restrict__ part, int nblk) {
    __shared__ int sc[256];
    const int t = threadIdx.x;
    const int v = (t < nblk) ? part[t] : 0;
    sc[t] = v;
    __syncthreads();
    for (int off = 1; off < 256; off <<= 1) {
        int u = (t >= off) ? sc[t - off] : 0;
        __syncthreads();
        sc[t] += u;
        __syncthreads();
    }
    part[t] = sc[t] - v;   // exclusive base per block
}

__global__ void scan_fin_kernel(const int* __restrict__ cnt, const int* __restrict__ part,
                                int* __restrict__ cur, int N) {
    __shared__ int sc[256];
    const int t = threadIdx.x, idx = blockIdx.x * 256 + t;
    const int v = (idx < N) ? cnt[idx] : 0;
    sc[t] = v;
    __syncthreads();
    for (int off = 1; off < 256; off <<= 1) {
        int u = (t >= off) ? sc[t - off] : 0;
        __syncthreads();
        sc[t] += u;
        __syncthreads();
    }
    if (idx < N) cur[idx] = sc[t] - v + part[blockIdx.x];
}

__global__ void scatter_kernel(const int* __restrict__ edst, int* __restrict__ cur,
                               int* __restrict__ spos, int E) {
    const int stride = gridDim.x * blockDim.x;
    for (int e = blockIdx.x * blockDim.x + threadIdx.x; e < E; e += stride) {
        int pos = atomicAdd(&cur[edst[e]], 1);
        spos[e] = pos;                       // coalesced write
    }
}

// node_feat f32 -> bf16 cache (one pass, 12.8 MB read / 6.4 MB write)
__global__ void cvt_nf_kernel(const float* __restrict__ nf, bf16* __restrict__ nfb, int total8) {
    const int i = blockIdx.x * blockDim.x + threadIdx.x;
    if (i < total8) {
        f32x4 a = ((const f32x4*)nf)[i*2], b = ((const f32x4*)nf)[i*2 + 1];
        bf16x8 v;
        #pragma unroll
        for (int k = 0; k < 4; ++k) { v[k] = (bf16)a[k]; v[4+k] = (bf16)b[k]; }
        ((bf16x8*)nfb)[i] = v;
    }
}

// ---------------------------------------------------------------------------
// Edge message MLP (bf16 MFMA), original edge order (efeat streams).
// nfb   != null: node gathers are direct bf16x8 loads (MFMA-ready).
// msgbuf!= null: messages scattered to msgbuf[spos[e]] (dst-sorted layout).
// msgbuf== null: fallback atomic scatter-add into agg (pre-zeroed).
// K-slot convention k' = 32*ks + 8*(lane>>4) + i for BOTH A and B fragments.
// C/D layout: col = nt*16 + (lane&15), row = 4*(lane>>4) + reg.
// LDS: W1f 24K + W2f 8K + HM 18K (hidden AND message tile, overlaid) = 51.7K
//      -> 3 blocks/CU. Overlay safe: same-wave DS ops complete in order
//      (lgkmcnt is in-order for DS); explicit lgkmcnt(0) before overwrite.
// ---------------------------------------------------------------------------
__launch_bounds__(256, 3)
__global__ void mp_edge_kernel(
    const float* __restrict__ node_feat,
    const bf16*  __restrict__ nfb,      // bf16 node cache or null
    const int*   __restrict__ esrc,
    const int*   __restrict__ edst,
    const float* __restrict__ efeat,
    const int*   __restrict__ spos,     // inverse perm or null
    const float* __restrict__ W1, const float* __restrict__ b1,
    const float* __restrict__ W2, const float* __restrict__ b2,
    bf16* __restrict__ msgbuf,          // sorted [E][64] messages, or null
    float* __restrict__ agg,            // fallback atomic target, or null
    int E)
{
    __shared__ __align__(16) bf16 W1f[6*4*64*8];   // 24 KB (ks,nt,lane,8)
    __shared__ __align__(16) bf16 W2f[2*4*64*8];   //  8 KB
    __shared__ __align__(16) bf16 HM[4][32*72];    // 18 KB hidden/msg overlay
    __shared__ float b1s[D], b2s[D];

    const int t    = threadIdx.x;
    const int lane = t & 63;
    const int w    = t >> 6;
    const int g    = lane >> 4;
    const int c    = lane & 15;

    for (int idx = t; idx < 6*4*64; idx += 256) {
        int l = idx & 63, nt = (idx >> 6) & 3, ks = idx >> 8;
        int k0 = ks*32 + (l >> 4)*8, col = nt*16 + (l & 15);
        bf16x8 v;
        #pragma unroll
        for (int i = 0; i < 8; ++i) v[i] = (bf16)W1[(k0 + i)*D + col];
        *(bf16x8*)&W1f[idx*8] = v;
    }
    for (int idx = t; idx < 2*4*64; idx += 256) {
        int l = idx & 63, nt = (idx >> 6) & 3, ks = idx >> 8;
        int k0 = ks*32 + (l >> 4)*8, col = nt*16 + (l & 15);
        bf16x8 v;
        #pragma unroll
        for (int i = 0; i < 8; ++i) v[i] = (bf16)W2[(k0 + i)*D + col];
        *(bf16x8*)&W2f[idx*8] = v;
    }
    if (t < D) { b1s[t] = b1[t]; b2s[t] = b2[t]; }
    __syncthreads();   // weights ready; the ONLY barrier

    bf16* hm = &HM[w][0];
    const int nwt = (E + EPW - 1) / EPW;
    const int t0  = blockIdx.x*4 + w;
    const int tstride = gridDim.x*4;

    // prefetched ids for the upcoming tile
    int nse0=0, nde0=0, nsp0=0, nse1=0, nde1=0, nsp1=0;
    if (t0 < nwt) {
        const int q0 = min(t0*EPW + c, E - 1);
        const int q1 = min(t0*EPW + 16 + c, E - 1);
        nse0 = esrc[q0]; nde0 = edst[q0];
        nse1 = esrc[q1]; nde1 = edst[q1];
        if (spos) { nsp0 = spos[q0]; nsp1 = spos[q1]; }
    }

    for (int tile = t0; tile < nwt; tile += tstride) {
        const int e0 = tile * EPW;
        const int se0 = nse0, de0 = nde0, sp0 = nsp0;
        const int se1 = nse1, de1 = nde1, sp1 = nsp1;
        // prefetch next tile's ids (overlaps with this tile's gathers/compute)
        const int tn = tile + tstride;
        if (tn < nwt) {
            const int q0 = min(tn*EPW + c, E - 1);
            const int q1 = min(tn*EPW + 16 + c, E - 1);
            nse0 = esrc[q0]; nde0 = edst[q0];
            nse1 = esrc[q1]; nde1 = edst[q1];
            if (spos) { nsp0 = spos[q0]; nsp1 = spos[q1]; }
        }
        const int r0 = min(e0 + c,      E - 1);
        const int r1 = min(e0 + 16 + c, E - 1);

        // ---- GEMM1: [32,192]@[192,64], A direct from global ----
        f32x4 acc0[4] = {f32x4{0,0,0,0}, f32x4{0,0,0,0}, f32x4{0,0,0,0}, f32x4{0,0,0,0}};
        f32x4 acc1[4] = {f32x4{0,0,0,0}, f32x4{0,0,0,0}, f32x4{0,0,0,0}, f32x4{0,0,0,0}};
        #pragma unroll
        for (int ks = 0; ks < 6; ++ks) {
            bf16x8 a0, a1;
            if (ks < 4) {
                const int row0 = (ks < 2) ? se0 : de0;
                const int row1 = (ks < 2) ? se1 : de1;
                const int coff = (ks & 1)*32 + g*8;
                if (nfb) {
                    a0 = *(const bf16x8*)&nfb[(size_t)row0*D + coff];
                    a1 = *(const bf16x8*)&nfb[(size_t)row1*D + coff];
                } else {
                    const float* p0 = node_feat + (size_t)row0*D + coff;
                    const float* p1 = node_feat + (size_t)row1*D + coff;
                    f32x4 xa = ((const f32x4*)p0)[0], xb = ((const f32x4*)p0)[1];
                    f32x4 ya = ((const f32x4*)p1)[0], yb = ((const f32x4*)p1)[1];
                    #pragma unroll
                    for (int i = 0; i < 4; ++i) {
                        a0[i] = (bf16)xa[i];  a0[4+i] = (bf16)xb[i];
                        a1[i] = (bf16)ya[i];  a1[4+i] = (bf16)yb[i];
                    }
                }
            } else {
                const int coff = (ks - 4)*32 + g*8;
                const float* p0 = efeat + (size_t)r0*D + coff;
                const float* p1 = efeat + (size_t)r1*D + coff;
                f32x4 xa = ((const f32x4*)p0)[0], xb = ((const f32x4*)p0)[1];
                f32x4 ya = ((const f32x4*)p1)[0], yb = ((const f32x4*)p1)[1];
                #pragma unroll
                for (int i = 0; i < 4; ++i) {
                    a0[i] = (bf16)xa[i];  a0[4+i] = (bf16)xb[i];
                    a1[i] = (bf16)ya[i];  a1[4+i] = (bf16)yb[i];
                }
            }
            #pragma unroll
            for (int n = 0; n < 4; ++n) {
                bf16x8 bb = *(const bf16x8*)&W1f[((ks*4 + n)*64 + lane)*8];
                acc0[n] = __builtin_amdgcn_mfma_f32_16x16x32_bf16(a0, bb, acc0[n], 0, 0, 0);
                acc1[n] = __builtin_amdgcn_mfma_f32_16x16x32_bf16(a1, bb, acc1[n], 0, 0, 0);
            }
        }

        // ---- bias + SiLU -> per-wave HM (bf16) ----
        #pragma unroll
        for (int n = 0; n < 4; ++n) {
            const int col = n*16 + c;
            const float bias = b1s[col];
            #pragma unroll
            for (int j = 0; j < 4; ++j) {
                hm[(g*4 + j)*72 + col]      = (bf16)silu_f(acc0[n][j] + bias);
                hm[(16 + g*4 + j)*72 + col] = (bf16)silu_f(acc1[n][j] + bias);
            }
        }

        // ---- GEMM2: [32,64]@[64,64] (intra-wave LDS ordering) ----
        f32x4 acc2a[4] = {f32x4{0,0,0,0}, f32x4{0,0,0,0}, f32x4{0,0,0,0}, f32x4{0,0,0,0}};
        f32x4 acc2b[4] = {f32x4{0,0,0,0}, f32x4{0,0,0,0}, f32x4{0,0,0,0}, f32x4{0,0,0,0}};
        #pragma unroll
        for (int ks = 0; ks < 2; ++ks) {
            bf16x8 a0 = *(const bf16x8*)&hm[c*72        + ks*32 + g*8];
            bf16x8 a1 = *(const bf16x8*)&hm[(16 + c)*72 + ks*32 + g*8];
            #pragma unroll
            for (int n = 0; n < 4; ++n) {
                bf16x8 bb = *(const bf16x8*)&W2f[((ks*4 + n)*64 + lane)*8];
                acc2a[n] = __builtin_amdgcn_mfma_f32_16x16x32_bf16(a0, bb, acc2a[n], 0, 0, 0);
                acc2b[n] = __builtin_amdgcn_mfma_f32_16x16x32_bf16(a1, bb, acc2b[n], 0, 0, 0);
            }
        }

        if (msgbuf) {
            // all GEMM2 hm-reads retired (DS in-order; MFMA consumed results)
            asm volatile("s_waitcnt lgkmcnt(0)" ::: "memory");
            // ---- messages (+bias) -> HM overlay (stride 72) ----
            #pragma unroll
            for (int n = 0; n < 4; ++n) {
                const int col = n*16 + c;
                const float bias = b2s[col];
                #pragma unroll
                for (int j = 0; j < 4; ++j) {
                    hm[(g*4 + j)*72 + col]      = (bf16)(acc2a[n][j] + bias);
                    hm[(16 + g*4 + j)*72 + col] = (bf16)(acc2b[n][j] + bias);
                }
            }
            // ---- scatter rows to sorted msgbuf positions (128B per row) ----
            #pragma unroll
            for (int it = 0; it < 4; ++it) {
                const int row   = (lane >> 3) + it*8;
                const int chunk = lane & 7;
                const int sp = (it < 2) ? __shfl(sp0, row) : __shfl(sp1, row - 16);
                if (e0 + row < E)
                    *(bf16x8*)&msgbuf[(size_t)sp*64 + chunk*8] =
                        *(const bf16x8*)&hm[row*72 + chunk*8];
            }
        } else {
            // ---- fallback: atomic scatter-add ----
            #pragma unroll
            for (int j = 0; j < 4; ++j) {
                const int row = g*4 + j;
                const int d0 = __shfl(de0, row);
                const int d1 = __shfl(de1, row);
                const bool ok0 = (e0 + row)      < E;
                const bool ok1 = (e0 + 16 + row) < E;
                #pragma unroll
                for (int n = 0; n < 4; ++n) {
                    const int col = n*16 + c;
                    if (ok0) atomicAdd(&agg[(size_t)d0*D + col], acc2a[n][j] + b2s[col]);
                    if (ok1) atomicAdd(&agg[(size_t)d1*D + col], acc2b[n][j] + b2s[col]);
                }
            }
        }
    }
}

// ---------------------------------------------------------------------------
// Streaming aggregate: msgbuf is dst-sorted, so node n's messages are rows
// [cur[n]-cnt[n], cur[n]) -- fully contiguous. One wave per node; 8 rows/pass
// (8 lanes x 16B per row); 3-round shfl_xor reduce over the row axis.
// Writes every node (no memset needed).
// ---------------------------------------------------------------------------
__launch_bounds__(256, 8)
__global__ void agg_kernel(const bf16* __restrict__ msgbuf,
                           const int* __restrict__ cnt,
                           const int* __restrict__ cur,
                           float* __restrict__ agg,
                           int N)
{
    const int lane = threadIdx.x & 63;
    const int w    = threadIdx.x >> 6;
    const int p    = lane >> 3;     // row within pass
    const int cb   = lane & 7;      // 8-col block
    for (int n = blockIdx.x*4 + w; n < N; n += gridDim.x*4) {
        const int end = cur[n];
        const int beg = end - cnt[n];
        float s[8] = {0,0,0,0,0,0,0,0};
        for (int i = beg + p; i < end; i += 8) {
            bf16x8 v = *(const bf16x8*)&msgbuf[(size_t)i*64 + cb*8];
            #pragma unroll
            for (int k = 0; k < 8; ++k) s[k] += (float)v[k];
        }
        #pragma unroll
        for (int off = 8; off < 64; off <<= 1) {
            #pragma unroll
            for (int k = 0; k < 8; ++k) s[k] += __shfl_xor(s[k], off);
        }
        if (lane < 8) {
            f32x4 lo = {s[0], s[1], s[2], s[3]};
            f32x4 hi = {s[4], s[5], s[6], s[7]};
            *(f32x4*)&agg[(size_t)n*D + lane*8]     = lo;
            *(f32x4*)&agg[(size_t)n*D + lane*8 + 4] = hi;
        }
    }
}

// ---------------------------------------------------------------------------
// Node update MLP as MFMA GEMM + residual + LayerNorm, in-place on agg.
// ---------------------------------------------------------------------------
__launch_bounds__(256, 4)
__global__ void node_gemm_kernel(
    const float* __restrict__ node_feat,
    const float* __restrict__ Wu1, const float* __restrict__ bu1,
    const float* __restrict__ Wu2, const float* __restrict__ bu2,
    const float* __restrict__ gamma, const float* __restrict__ beta,
    float* __restrict__ inout, int N)
{
    __shared__ __align__(16) bf16 Wf1[2*4*64*8];   // 8 KB
    __shared__ __align__(16) bf16 Wf2[2*4*64*8];   // 8 KB
    __shared__ __align__(16) bf16 Hs[4][16*72];    // 9 KB
    __shared__ float b1s[D], b2s[D], gs[D], bs[D];

    const int t    = threadIdx.x;
    const int lane = t & 63;
    const int w    = t >> 6;
    const int g    = lane >> 4;
    const int c    = lane & 15;

    for (int idx = t; idx < 2*4*64; idx += 256) {
        int l = idx & 63, nt = (idx >> 6) & 3, ks = idx >> 8;
        int k0 = ks*32 + (l >> 4)*8, col = nt*16 + (l & 15);
        bf16x8 v1, v2;
        #pragma unroll
        for (int i = 0; i < 8; ++i) {
            v1[i] = (bf16)Wu1[(k0 + i)*D + col];
            v2[i] = (bf16)Wu2[(k0 + i)*D + col];
        }
        *(bf16x8*)&Wf1[idx*8] = v1;
        *(bf16x8*)&Wf2[idx*8] = v2;
    }
    if (t < D) { b1s[t] = bu1[t]; b2s[t] = bu2[t]; gs[t] = gamma[t]; bs[t] = beta[t]; }
    __syncthreads();

    const int base = blockIdx.x*64 + w*16;
    if (base >= N) return;
    bf16* hs = &Hs[w][0];

    f32x4 acc[4] = {f32x4{0,0,0,0}, f32x4{0,0,0,0}, f32x4{0,0,0,0}, f32x4{0,0,0,0}};
    #pragma unroll
    for (int ks = 0; ks < 2; ++ks) {
        const int rowA = min(base + c, N - 1);
        const float* p = inout + (size_t)rowA*D + ks*32 + g*8;
        f32x4 xa = ((const f32x4*)p)[0], xb = ((const f32x4*)p)[1];
        bf16x8 a;
        #pragma unroll
        for (int i = 0; i < 4; ++i) { a[i] = (bf16)xa[i]; a[4+i] = (bf16)xb[i]; }
        #pragma unroll
        for (int n = 0; n < 4; ++n) {
            bf16x8 bb = *(const bf16x8*)&Wf1[((ks*4 + n)*64 + lane)*8];
            acc[n] = __builtin_amdgcn_mfma_f32_16x16x32_bf16(a, bb, acc[n], 0, 0, 0);
        }
    }
    #pragma unroll
    for (int n = 0; n < 4; ++n) {
        const int col = n*16 + c;
        const float bias = b1s[col];
        #pragma unroll
        for (int j = 0; j < 4; ++j)
            hs[(g*4 + j)*72 + col] = (bf16)silu_f(acc[n][j] + bias);
    }

    f32x4 acc2[4] = {f32x4{0,0,0,0}, f32x4{0,0,0,0}, f32x4{0,0,0,0}, f32x4{0,0,0,0}};
    #pragma unroll
    for (int ks = 0; ks < 2; ++ks) {
        bf16x8 a = *(const bf16x8*)&hs[c*72 + ks*32 + g*8];
        #pragma unroll
        for (int n = 0; n < 4; ++n) {
            bf16x8 bb = *(const bf16x8*)&Wf2[((ks*4 + n)*64 + lane)*8];
            acc2[n] = __builtin_amdgcn_mfma_f32_16x16x32_bf16(a, bb, acc2[n], 0, 0, 0);
        }
    }

    float y[4][4];
    #pragma unroll
    for (int n = 0; n < 4; ++n) {
        const int col = n*16 + c;
        #pragma unroll
        for (int j = 0; j < 4; ++j) {
            const int row = base + g*4 + j;
            const float x0 = (row < N) ? node_feat[(size_t)row*D + col] : 0.f;
            y[n][j] = x0 + acc2[n][j] + b2s[col];
        }
    }
    #pragma unroll
    for (int j = 0; j < 4; ++j) {
        float s1 = 0.f, s2 = 0.f;
        #pragma unroll
        for (int n = 0; n < 4; ++n) { s1 += y[n][j]; s2 += y[n][j]*y[n][j]; }
        #pragma unroll
        for (int m = 1; m < 16; m <<= 1) {
            s1 += __shfl_xor(s1, m);
            s2 += __shfl_xor(s2, m);
        }
        const float mu  = s1 * (1.0f/64.0f);
        const float var = s2 * (1.0f/64.0f) - mu*mu;
        const float rs  = rsqrtf(var + 1e-5f);
        const int row = base + g*4 + j;
        if (row < N) {
            #pragma unroll
            for (int n = 0; n < 4; ++n) {
                const int col = n*16 + c;
                inout[(size_t)row*D + col] = (y[n][j] - mu)*rs*gs[col] + bs[col];
            }
        }
    }
}

extern "C" void kernel_launch(void* const* d_in, const int* in_sizes, int n_in,
                              void* d_out, int out_size, void* d_ws, size_t ws_size,
                              hipStream_t stream) {
    const float* node_feat = (const float*)d_in[0];
    const int*   esrc      = (const int*)d_in[1];
    const int*   edst      = (const int*)d_in[2];
    const float* efeat     = (const float*)d_in[3];
    const float* W_m1      = (const float*)d_in[4];
    const float* b_m1      = (const float*)d_in[5];
    const float* W_m2      = (const float*)d_in[6];
    const float* b_m2      = (const float*)d_in[7];
    const float* W_u1      = (const float*)d_in[8];
    const float* b_u1      = (const float*)d_in[9];
    const float* W_u2      = (const float*)d_in[10];
    const float* b_u2      = (const float*)d_in[11];
    const float* ln_gamma  = (const float*)d_in[12];
    const float* ln_beta   = (const float*)d_in[13];

    float* out = (float*)d_out;
    const int E = in_sizes[1];
    const int N = in_sizes[0] / D;

    // ws layout: msgbuf bf16[E*64] | spos[E] | cnt[N] | cur[N] | part[256] | nfb bf16[N*64]
    const size_t msg_bytes = (((size_t)E * D * 2) + 255) & ~(size_t)255;
    const size_t int_bytes = ((sizeof(int) * ((size_t)E + 2*(size_t)N + 256)) + 255) & ~(size_t)255;
    const size_t nfb_bytes = (((size_t)N * D * 2) + 255) & ~(size_t)255;
    const size_t need_csr  = msg_bytes + int_bytes;
    const size_t need_full = need_csr + nfb_bytes;

    const int nwt   = (E + EPW - 1) / EPW;
    const int nblk  = (nwt + 3) / 4;
    const int grid1 = nblk < 768 ? nblk : 768;      // 3 blocks/CU persistent
    const int gridN = (N + 63) / 64;
    const int nchunk = (N + 255) / 256;

    const bool csr     = ws_size >= need_csr;
    const bool use_nfb = ws_size >= (csr ? need_full : nfb_bytes);

    bf16* msgbuf = nullptr;
    int  *spos = nullptr, *cnt = nullptr, *cur = nullptr, *part = nullptr;
    bf16* nfb = nullptr;

    if (csr) {
        msgbuf = (bf16*)d_ws;
        spos   = (int*)((char*)d_ws + msg_bytes);
        cnt    = spos + E;
        cur    = cnt + N;
        part   = cur + N;
        if (use_nfb) nfb = (bf16*)((char*)d_ws + need_csr);
    } else if (use_nfb) {
        nfb = (bf16*)d_ws;
    }

    if (use_nfb) {
        const int total8 = N * D / 8;
        cvt_nf_kernel<<<(total8 + 255)/256, 256, 0, stream>>>(node_feat, nfb, total8);
    }

    if (csr) {
        hipMemsetAsync(cnt, 0, sizeof(int)*(size_t)N, stream);
        hist_kernel     <<<1024, 256, 0, stream>>>(edst, cnt, E);
        scan_part_kernel<<<nchunk, 256, 0, stream>>>(cnt, part, N);
        scan_base_kernel<<<1, 256, 0, stream>>>(part, nchunk);
        scan_fin_kernel <<<nchunk, 256, 0, stream>>>(cnt, part, cur, N);
        scatter_kernel  <<<1024, 256, 0, stream>>>(edst, cur, spos, E);

        mp_edge_kernel<<<grid1, 256, 0, stream>>>(node_feat, nfb, esrc, edst, efeat, spos,
                                                  W_m1, b_m1, W_m2, b_m2,
                                                  msgbuf, nullptr, E);
        agg_kernel<<<2048, 256, 0, stream>>>(msgbuf, cnt, cur, out, N);
    } else {
        hipMemsetAsync(out, 0, (size_t)N * D * sizeof(float), stream);
        mp_edge_kernel<<<grid1, 256, 0, stream>>>(node_feat, nfb, esrc, edst, efeat, nullptr,
                                                  W_m1, b_m1, W_m2, b_m2,
                                                  nullptr, out, E);
    }

    node_gemm_kernel<<<gridN, 256, 0, stream>>>(node_feat, W_u1, b_u1, W_u2, b_u2,
                                                ln_gamma, ln_beta, out, N);
}

// Round 6
// 249.276 us; speedup vs baseline: 2.6092x; 1.0082x over previous
//
#include <hip/hip_runtime.h>
#include <stdint.h>

typedef __bf16 bf16;
typedef __attribute__((ext_vector_type(8))) bf16 bf16x8;
typedef __attribute__((ext_vector_type(4))) float f32x4;

#define D 64
#define EPW 32   // edges per wave-tile

__device__ __forceinline__ float silu_f(float x) {
    return x / (1.0f + __expf(-x));
}

// ---------------------------------------------------------------------------
// Counting sort by edge_dst: hist -> 3-kernel scan -> scatter (inverse perm).
// ---------------------------------------------------------------------------
__global__ void hist_kernel(const int* __restrict__ edst, int* __restrict__ cnt, int E) {
    const int stride = gridDim.x * blockDim.x;
    for (int e = blockIdx.x * blockDim.x + threadIdx.x; e < E; e += stride)
        atomicAdd(&cnt[edst[e]], 1);
}

__global__ void scan_part_kernel(const int* __restrict__ cnt, int* __restrict__ part, int N) {
    __shared__ int red[256];
    const int t = threadIdx.x, idx = blockIdx.x * 256 + t;
    red[t] = (idx < N) ? cnt[idx] : 0;
    __syncthreads();
    for (int off = 128; off; off >>= 1) {
        if (t < off) red[t] += red[t + off];
        __syncthreads();
    }
    if (t == 0) part[blockIdx.x] = red[0];
}

__global__ void scan_base_kernel(int* __restrict__ part, int nblk) {
    __shared__ int sc[256];
    const int t = threadIdx.x;
    const int v = (t < nblk) ? part[t] : 0;
    sc[t] = v;
    __syncthreads();
    for (int off = 1; off < 256; off <<= 1) {
        int u = (t >= off) ? sc[t - off] : 0;
        __syncthreads();
        sc[t] += u;
        __syncthreads();
    }
    part[t] = sc[t] - v;   // exclusive base per block
}

__global__ void scan_fin_kernel(const int* __restrict__ cnt, const int* __restrict__ part,
                                int* __restrict__ cur, int N) {
    __shared__ int sc[256];
    const int t = threadIdx.x, idx = blockIdx.x * 256 + t;
    const int v = (idx < N) ? cnt[idx] : 0;
    sc[t] = v;
    __syncthreads();
    for (int off = 1; off < 256; off <<= 1) {
        int u = (t >= off) ? sc[t - off] : 0;
        __syncthreads();
        sc[t] += u;
        __syncthreads();
    }
    if (idx < N) cur[idx] = sc[t] - v + part[blockIdx.x];
}

__global__ void scatter_kernel(const int* __restrict__ edst, int* __restrict__ cur,
                               int* __restrict__ spos, int E) {
    const int stride = gridDim.x * blockDim.x;
    for (int e = blockIdx.x * blockDim.x + threadIdx.x; e < E; e += stride) {
        int pos = atomicAdd(&cur[edst[e]], 1);
        spos[e] = pos;                       // coalesced write
    }
}

// node_feat f32 -> bf16 cache
__global__ void cvt_nf_kernel(const float* __restrict__ nf, bf16* __restrict__ nfb, int total8) {
    const int i = blockIdx.x * blockDim.x + threadIdx.x;
    if (i < total8) {
        f32x4 a = ((const f32x4*)nf)[i*2], b = ((const f32x4*)nf)[i*2 + 1];
        bf16x8 v;
        #pragma unroll
        for (int k = 0; k < 4; ++k) { v[k] = (bf16)a[k]; v[4+k] = (bf16)b[k]; }
        ((bf16x8*)nfb)[i] = v;
    }
}

// ---------------------------------------------------------------------------
// Edge message MLP (bf16 MFMA), original edge order (efeat streams).
// GEMM1 is split into LOAD PHASE (all 16 independent global loads issued
// into named registers -> single latency exposure) then COMPUTE PHASE.
// K-slot convention k' = 32*ks + 8*(lane>>4) + i for BOTH A and B fragments.
// C/D layout: col = nt*16 + (lane&15), row = 4*(lane>>4) + reg.
// LDS: W1f 24K + W2f 8K + HM 18K (hidden/msg overlay) = 51.7K -> 3 blocks/CU.
// ---------------------------------------------------------------------------
__launch_bounds__(256, 3)
__global__ void mp_edge_kernel(
    const float* __restrict__ node_feat,
    const bf16*  __restrict__ nfb,      // bf16 node cache or null
    const int*   __restrict__ esrc,
    const int*   __restrict__ edst,
    const float* __restrict__ efeat,
    const int*   __restrict__ spos,     // inverse perm or null
    const float* __restrict__ W1, const float* __restrict__ b1,
    const float* __restrict__ W2, const float* __restrict__ b2,
    bf16* __restrict__ msgbuf,          // sorted [E][64] messages, or null
    float* __restrict__ agg,            // fallback atomic target, or null
    int E)
{
    __shared__ __align__(16) bf16 W1f[6*4*64*8];   // 24 KB (ks,nt,lane,8)
    __shared__ __align__(16) bf16 W2f[2*4*64*8];   //  8 KB
    __shared__ __align__(16) bf16 HM[4][32*72];    // 18 KB hidden/msg overlay
    __shared__ float b1s[D], b2s[D];

    const int t    = threadIdx.x;
    const int lane = t & 63;
    const int w    = t >> 6;
    const int g    = lane >> 4;
    const int c    = lane & 15;

    for (int idx = t; idx < 6*4*64; idx += 256) {
        int l = idx & 63, nt = (idx >> 6) & 3, ks = idx >> 8;
        int k0 = ks*32 + (l >> 4)*8, col = nt*16 + (l & 15);
        bf16x8 v;
        #pragma unroll
        for (int i = 0; i < 8; ++i) v[i] = (bf16)W1[(k0 + i)*D + col];
        *(bf16x8*)&W1f[idx*8] = v;
    }
    for (int idx = t; idx < 2*4*64; idx += 256) {
        int l = idx & 63, nt = (idx >> 6) & 3, ks = idx >> 8;
        int k0 = ks*32 + (l >> 4)*8, col = nt*16 + (l & 15);
        bf16x8 v;
        #pragma unroll
        for (int i = 0; i < 8; ++i) v[i] = (bf16)W2[(k0 + i)*D + col];
        *(bf16x8*)&W2f[idx*8] = v;
    }
    if (t < D) { b1s[t] = b1[t]; b2s[t] = b2[t]; }
    __syncthreads();   // weights ready; the ONLY barrier

    bf16* hm = &HM[w][0];
    const int nwt = (E + EPW - 1) / EPW;
    const int t0  = blockIdx.x*4 + w;
    const int tstride = gridDim.x*4;

    // prefetched ids for the upcoming tile
    int nse0=0, nde0=0, nsp0=0, nse1=0, nde1=0, nsp1=0;
    if (t0 < nwt) {
        const int q0 = min(t0*EPW + c, E - 1);
        const int q1 = min(t0*EPW + 16 + c, E - 1);
        nse0 = esrc[q0]; nde0 = edst[q0];
        nse1 = esrc[q1]; nde1 = edst[q1];
        if (spos) { nsp0 = spos[q0]; nsp1 = spos[q1]; }
    }

    for (int tile = t0; tile < nwt; tile += tstride) {
        const int e0 = tile * EPW;
        const int se0 = nse0, de0 = nde0, sp0 = nsp0;
        const int se1 = nse1, de1 = nde1, sp1 = nsp1;
        const int tn = tile + tstride;
        if (tn < nwt) {     // prefetch next tile's ids
            const int q0 = min(tn*EPW + c, E - 1);
            const int q1 = min(tn*EPW + 16 + c, E - 1);
            nse0 = esrc[q0]; nde0 = edst[q0];
            nse1 = esrc[q1]; nde1 = edst[q1];
            if (spos) { nsp0 = spos[q0]; nsp1 = spos[q1]; }
        }
        const int r0 = min(e0 + c,      E - 1);
        const int r1 = min(e0 + 16 + c, E - 1);

        // ================= LOAD PHASE: 16 independent loads =================
        bf16x8 an[8];          // node gathers [ks<4][row0/1]
        f32x4  ef[8];          // efeat stream [ks2][row][half]
        if (nfb) {
            #pragma unroll
            for (int ks = 0; ks < 4; ++ks) {
                const int row0 = (ks < 2) ? se0 : de0;
                const int row1 = (ks < 2) ? se1 : de1;
                const int coff = (ks & 1)*32 + g*8;
                an[ks*2]   = *(const bf16x8*)&nfb[(size_t)row0*D + coff];
                an[ks*2+1] = *(const bf16x8*)&nfb[(size_t)row1*D + coff];
            }
        } else {
            #pragma unroll
            for (int ks = 0; ks < 4; ++ks) {
                const int row0 = (ks < 2) ? se0 : de0;
                const int row1 = (ks < 2) ? se1 : de1;
                const int coff = (ks & 1)*32 + g*8;
                const float* p0 = node_feat + (size_t)row0*D + coff;
                const float* p1 = node_feat + (size_t)row1*D + coff;
                f32x4 xa = ((const f32x4*)p0)[0], xb = ((const f32x4*)p0)[1];
                f32x4 ya = ((const f32x4*)p1)[0], yb = ((const f32x4*)p1)[1];
                bf16x8 a0, a1;
                #pragma unroll
                for (int i = 0; i < 4; ++i) {
                    a0[i] = (bf16)xa[i];  a0[4+i] = (bf16)xb[i];
                    a1[i] = (bf16)ya[i];  a1[4+i] = (bf16)yb[i];
                }
                an[ks*2] = a0; an[ks*2+1] = a1;
            }
        }
        #pragma unroll
        for (int ks2 = 0; ks2 < 2; ++ks2) {
            const int coff = ks2*32 + g*8;
            const float* p0 = efeat + (size_t)r0*D + coff;
            const float* p1 = efeat + (size_t)r1*D + coff;
            ef[ks2*4+0] = ((const f32x4*)p0)[0];
            ef[ks2*4+1] = ((const f32x4*)p0)[1];
            ef[ks2*4+2] = ((const f32x4*)p1)[0];
            ef[ks2*4+3] = ((const f32x4*)p1)[1];
        }

        // ================= COMPUTE PHASE: GEMM1 =================
        f32x4 acc0[4] = {f32x4{0,0,0,0}, f32x4{0,0,0,0}, f32x4{0,0,0,0}, f32x4{0,0,0,0}};
        f32x4 acc1[4] = {f32x4{0,0,0,0}, f32x4{0,0,0,0}, f32x4{0,0,0,0}, f32x4{0,0,0,0}};
        #pragma unroll
        for (int ks = 0; ks < 4; ++ks) {
            #pragma unroll
            for (int n = 0; n < 4; ++n) {
                bf16x8 bb = *(const bf16x8*)&W1f[((ks*4 + n)*64 + lane)*8];
                acc0[n] = __builtin_amdgcn_mfma_f32_16x16x32_bf16(an[ks*2],   bb, acc0[n], 0, 0, 0);
                acc1[n] = __builtin_amdgcn_mfma_f32_16x16x32_bf16(an[ks*2+1], bb, acc1[n], 0, 0, 0);
            }
        }
        #pragma unroll
        for (int ks2 = 0; ks2 < 2; ++ks2) {
            bf16x8 a0, a1;
            #pragma unroll
            for (int i = 0; i < 4; ++i) {
                a0[i]   = (bf16)ef[ks2*4+0][i];
                a0[4+i] = (bf16)ef[ks2*4+1][i];
                a1[i]   = (bf16)ef[ks2*4+2][i];
                a1[4+i] = (bf16)ef[ks2*4+3][i];
            }
            #pragma unroll
            for (int n = 0; n < 4; ++n) {
                bf16x8 bb = *(const bf16x8*)&W1f[(((ks2+4)*4 + n)*64 + lane)*8];
                acc0[n] = __builtin_amdgcn_mfma_f32_16x16x32_bf16(a0, bb, acc0[n], 0, 0, 0);
                acc1[n] = __builtin_amdgcn_mfma_f32_16x16x32_bf16(a1, bb, acc1[n], 0, 0, 0);
            }
        }

        // ---- bias + SiLU -> per-wave HM (bf16) ----
        #pragma unroll
        for (int n = 0; n < 4; ++n) {
            const int col = n*16 + c;
            const float bias = b1s[col];
            #pragma unroll
            for (int j = 0; j < 4; ++j) {
                hm[(g*4 + j)*72 + col]      = (bf16)silu_f(acc0[n][j] + bias);
                hm[(16 + g*4 + j)*72 + col] = (bf16)silu_f(acc1[n][j] + bias);
            }
        }

        // ---- GEMM2: [32,64]@[64,64] (intra-wave LDS ordering) ----
        f32x4 acc2a[4] = {f32x4{0,0,0,0}, f32x4{0,0,0,0}, f32x4{0,0,0,0}, f32x4{0,0,0,0}};
        f32x4 acc2b[4] = {f32x4{0,0,0,0}, f32x4{0,0,0,0}, f32x4{0,0,0,0}, f32x4{0,0,0,0}};
        #pragma unroll
        for (int ks = 0; ks < 2; ++ks) {
            bf16x8 a0 = *(const bf16x8*)&hm[c*72        + ks*32 + g*8];
            bf16x8 a1 = *(const bf16x8*)&hm[(16 + c)*72 + ks*32 + g*8];
            #pragma unroll
            for (int n = 0; n < 4; ++n) {
                bf16x8 bb = *(const bf16x8*)&W2f[((ks*4 + n)*64 + lane)*8];
                acc2a[n] = __builtin_amdgcn_mfma_f32_16x16x32_bf16(a0, bb, acc2a[n], 0, 0, 0);
                acc2b[n] = __builtin_amdgcn_mfma_f32_16x16x32_bf16(a1, bb, acc2b[n], 0, 0, 0);
            }
        }

        if (msgbuf) {
            asm volatile("s_waitcnt lgkmcnt(0)" ::: "memory");
            // ---- messages (+bias) -> HM overlay ----
            #pragma unroll
            for (int n = 0; n < 4; ++n) {
                const int col = n*16 + c;
                const float bias = b2s[col];
                #pragma unroll
                for (int j = 0; j < 4; ++j) {
                    hm[(g*4 + j)*72 + col]      = (bf16)(acc2a[n][j] + bias);
                    hm[(16 + g*4 + j)*72 + col] = (bf16)(acc2b[n][j] + bias);
                }
            }
            // ---- scatter rows to sorted msgbuf positions ----
            #pragma unroll
            for (int it = 0; it < 4; ++it) {
                const int row   = (lane >> 3) + it*8;
                const int chunk = lane & 7;
                const int sp = (it < 2) ? __shfl(sp0, row) : __shfl(sp1, row - 16);
                if (e0 + row < E)
                    *(bf16x8*)&msgbuf[(size_t)sp*64 + chunk*8] =
                        *(const bf16x8*)&hm[row*72 + chunk*8];
            }
        } else {
            // ---- fallback: atomic scatter-add ----
            #pragma unroll
            for (int j = 0; j < 4; ++j) {
                const int row = g*4 + j;
                const int d0 = __shfl(de0, row);
                const int d1 = __shfl(de1, row);
                const bool ok0 = (e0 + row)      < E;
                const bool ok1 = (e0 + 16 + row) < E;
                #pragma unroll
                for (int n = 0; n < 4; ++n) {
                    const int col = n*16 + c;
                    if (ok0) atomicAdd(&agg[(size_t)d0*D + col], acc2a[n][j] + b2s[col]);
                    if (ok1) atomicAdd(&agg[(size_t)d1*D + col], acc2b[n][j] + b2s[col]);
                }
            }
        }
    }
}

// ---------------------------------------------------------------------------
// Streaming aggregate over dst-sorted msgbuf (contiguous runs per node).
// ---------------------------------------------------------------------------
__launch_bounds__(256, 8)
__global__ void agg_kernel(const bf16* __restrict__ msgbuf,
                           const int* __restrict__ cnt,
                           const int* __restrict__ cur,
                           float* __restrict__ agg,
                           int N)
{
    const int lane = threadIdx.x & 63;
    const int w    = threadIdx.x >> 6;
    const int p    = lane >> 3;     // row within pass
    const int cb   = lane & 7;      // 8-col block
    for (int n = blockIdx.x*4 + w; n < N; n += gridDim.x*4) {
        const int end = cur[n];
        const int beg = end - cnt[n];
        float s[8] = {0,0,0,0,0,0,0,0};
        for (int i = beg + p; i < end; i += 8) {
            bf16x8 v = *(const bf16x8*)&msgbuf[(size_t)i*64 + cb*8];
            #pragma unroll
            for (int k = 0; k < 8; ++k) s[k] += (float)v[k];
        }
        #pragma unroll
        for (int off = 8; off < 64; off <<= 1) {
            #pragma unroll
            for (int k = 0; k < 8; ++k) s[k] += __shfl_xor(s[k], off);
        }
        if (lane < 8) {
            f32x4 lo = {s[0], s[1], s[2], s[3]};
            f32x4 hi = {s[4], s[5], s[6], s[7]};
            *(f32x4*)&agg[(size_t)n*D + lane*8]     = lo;
            *(f32x4*)&agg[(size_t)n*D + lane*8 + 4] = hi;
        }
    }
}

// ---------------------------------------------------------------------------
// Node update MLP as MFMA GEMM + residual + LayerNorm, in-place on agg.
// ---------------------------------------------------------------------------
__launch_bounds__(256, 4)
__global__ void node_gemm_kernel(
    const float* __restrict__ node_feat,
    const float* __restrict__ Wu1, const float* __restrict__ bu1,
    const float* __restrict__ Wu2, const float* __restrict__ bu2,
    const float* __restrict__ gamma, const float* __restrict__ beta,
    float* __restrict__ inout, int N)
{
    __shared__ __align__(16) bf16 Wf1[2*4*64*8];   // 8 KB
    __shared__ __align__(16) bf16 Wf2[2*4*64*8];   // 8 KB
    __shared__ __align__(16) bf16 Hs[4][16*72];    // 9 KB
    __shared__ float b1s[D], b2s[D], gs[D], bs[D];

    const int t    = threadIdx.x;
    const int lane = t & 63;
    const int w    = t >> 6;
    const int g    = lane >> 4;
    const int c    = lane & 15;

    for (int idx = t; idx < 2*4*64; idx += 256) {
        int l = idx & 63, nt = (idx >> 6) & 3, ks = idx >> 8;
        int k0 = ks*32 + (l >> 4)*8, col = nt*16 + (l & 15);
        bf16x8 v1, v2;
        #pragma unroll
        for (int i = 0; i < 8; ++i) {
            v1[i] = (bf16)Wu1[(k0 + i)*D + col];
            v2[i] = (bf16)Wu2[(k0 + i)*D + col];
        }
        *(bf16x8*)&Wf1[idx*8] = v1;
        *(bf16x8*)&Wf2[idx*8] = v2;
    }
    if (t < D) { b1s[t] = bu1[t]; b2s[t] = bu2[t]; gs[t] = gamma[t]; bs[t] = beta[t]; }
    __syncthreads();

    const int base = blockIdx.x*64 + w*16;
    if (base >= N) return;
    bf16* hs = &Hs[w][0];

    f32x4 acc[4] = {f32x4{0,0,0,0}, f32x4{0,0,0,0}, f32x4{0,0,0,0}, f32x4{0,0,0,0}};
    #pragma unroll
    for (int ks = 0; ks < 2; ++ks) {
        const int rowA = min(base + c, N - 1);
        const float* p = inout + (size_t)rowA*D + ks*32 + g*8;
        f32x4 xa = ((const f32x4*)p)[0], xb = ((const f32x4*)p)[1];
        bf16x8 a;
        #pragma unroll
        for (int i = 0; i < 4; ++i) { a[i] = (bf16)xa[i]; a[4+i] = (bf16)xb[i]; }
        #pragma unroll
        for (int n = 0; n < 4; ++n) {
            bf16x8 bb = *(const bf16x8*)&Wf1[((ks*4 + n)*64 + lane)*8];
            acc[n] = __builtin_amdgcn_mfma_f32_16x16x32_bf16(a, bb, acc[n], 0, 0, 0);
        }
    }
    #pragma unroll
    for (int n = 0; n < 4; ++n) {
        const int col = n*16 + c;
        const float bias = b1s[col];
        #pragma unroll
        for (int j = 0; j < 4; ++j)
            hs[(g*4 + j)*72 + col] = (bf16)silu_f(acc[n][j] + bias);
    }

    f32x4 acc2[4] = {f32x4{0,0,0,0}, f32x4{0,0,0,0}, f32x4{0,0,0,0}, f32x4{0,0,0,0}};
    #pragma unroll
    for (int ks = 0; ks < 2; ++ks) {
        bf16x8 a = *(const bf16x8*)&hs[c*72 + ks*32 + g*8];
        #pragma unroll
        for (int n = 0; n < 4; ++n) {
            bf16x8 bb = *(const bf16x8*)&Wf2[((ks*4 + n)*64 + lane)*8];
            acc2[n] = __builtin_amdgcn_mfma_f32_16x16x32_bf16(a, bb, acc2[n], 0, 0, 0);
        }
    }

    float y[4][4];
    #pragma unroll
    for (int n = 0; n < 4; ++n) {
        const int col = n*16 + c;
        #pragma unroll
        for (int j = 0; j < 4; ++j) {
            const int row = base + g*4 + j;
            const float x0 = (row < N) ? node_feat[(size_t)row*D + col] : 0.f;
            y[n][j] = x0 + acc2[n][j] + b2s[col];
        }
    }
    #pragma unroll
    for (int j = 0; j < 4; ++j) {
        float s1 = 0.f, s2 = 0.f;
        #pragma unroll
        for (int n = 0; n < 4; ++n) { s1 += y[n][j]; s2 += y[n][j]*y[n][j]; }
        #pragma unroll
        for (int m = 1; m < 16; m <<= 1) {
            s1 += __shfl_xor(s1, m);
            s2 += __shfl_xor(s2, m);
        }
        const float mu  = s1 * (1.0f/64.0f);
        const float var = s2 * (1.0f/64.0f) - mu*mu;
        const float rs  = rsqrtf(var + 1e-5f);
        const int row = base + g*4 + j;
        if (row < N) {
            #pragma unroll
            for (int n = 0; n < 4; ++n) {
                const int col = n*16 + c;
                inout[(size_t)row*D + col] = (y[n][j] - mu)*rs*gs[col] + bs[col];
            }
        }
    }
}

extern "C" void kernel_launch(void* const* d_in, const int* in_sizes, int n_in,
                              void* d_out, int out_size, void* d_ws, size_t ws_size,
                              hipStream_t stream) {
    const float* node_feat = (const float*)d_in[0];
    const int*   esrc      = (const int*)d_in[1];
    const int*   edst      = (const int*)d_in[2];
    const float* efeat     = (const float*)d_in[3];
    const float* W_m1      = (const float*)d_in[4];
    const float* b_m1      = (const float*)d_in[5];
    const float* W_m2      = (const float*)d_in[6];
    const float* b_m2      = (const float*)d_in[7];
    const float* W_u1      = (const float*)d_in[8];
    const float* b_u1      = (const float*)d_in[9];
    const float* W_u2      = (const float*)d_in[10];
    const float* b_u2      = (const float*)d_in[11];
    const float* ln_gamma  = (const float*)d_in[12];
    const float* ln_beta   = (const float*)d_in[13];

    float* out = (float*)d_out;
    const int E = in_sizes[1];
    const int N = in_sizes[0] / D;

    // ws layout: msgbuf bf16[E*64] | spos[E] | cnt[N] | cur[N] | part[256] | nfb bf16[N*64]
    const size_t msg_bytes = (((size_t)E * D * 2) + 255) & ~(size_t)255;
    const size_t int_bytes = ((sizeof(int) * ((size_t)E + 2*(size_t)N + 256)) + 255) & ~(size_t)255;
    const size_t nfb_bytes = (((size_t)N * D * 2) + 255) & ~(size_t)255;
    const size_t need_csr  = msg_bytes + int_bytes;
    const size_t need_full = need_csr + nfb_bytes;

    const int nwt   = (E + EPW - 1) / EPW;
    const int nblk  = (nwt + 3) / 4;
    const int grid1 = nblk < 768 ? nblk : 768;      // 3 blocks/CU persistent
    const int gridN = (N + 63) / 64;
    const int nchunk = (N + 255) / 256;

    const bool csr     = ws_size >= need_csr;
    const bool use_nfb = ws_size >= (csr ? need_full : nfb_bytes);

    bf16* msgbuf = nullptr;
    int  *spos = nullptr, *cnt = nullptr, *cur = nullptr, *part = nullptr;
    bf16* nfb = nullptr;

    if (csr) {
        msgbuf = (bf16*)d_ws;
        spos   = (int*)((char*)d_ws + msg_bytes);
        cnt    = spos + E;
        cur    = cnt + N;
        part   = cur + N;
        if (use_nfb) nfb = (bf16*)((char*)d_ws + need_csr);
    } else if (use_nfb) {
        nfb = (bf16*)d_ws;
    }

    if (use_nfb) {
        const int total8 = N * D / 8;
        cvt_nf_kernel<<<(total8 + 255)/256, 256, 0, stream>>>(node_feat, nfb, total8);
    }

    if (csr) {
        hipMemsetAsync(cnt, 0, sizeof(int)*(size_t)N, stream);
        hist_kernel     <<<1024, 256, 0, stream>>>(edst, cnt, E);
        scan_part_kernel<<<nchunk, 256, 0, stream>>>(cnt, part, N);
        scan_base_kernel<<<1, 256, 0, stream>>>(part, nchunk);
        scan_fin_kernel <<<nchunk, 256, 0, stream>>>(cnt, part, cur, N);
        scatter_kernel  <<<1024, 256, 0, stream>>>(edst, cur, spos, E);

        mp_edge_kernel<<<grid1, 256, 0, stream>>>(node_feat, nfb, esrc, edst, efeat, spos,
                                                  W_m1, b_m1, W_m2, b_m2,
                                                  msgbuf, nullptr, E);
        agg_kernel<<<2048, 256, 0, stream>>>(msgbuf, cnt, cur, out, N);
    } else {
        hipMemsetAsync(out, 0, (size_t)N * D * sizeof(float), stream);
        mp_edge_kernel<<<grid1, 256, 0, stream>>>(node_feat, nfb, esrc, edst, efeat, nullptr,
                                                  W_m1, b_m1, W_m2, b_m2,
                                                  nullptr, out, E);
    }

    node_gemm_kernel<<<gridN, 256, 0, stream>>>(node_feat, W_u1, b_u1, W_u2, b_u2,
                                                ln_gamma, ln_beta, out, N);
}